// Round 17
// baseline (225.263 us; speedup 1.0000x reference)
//
#include <hip/hip_runtime.h>
#include <math.h>

#define BDIM 8
#define IMG 224
#define PP 16
#define GG 14
#define NN 196
#define PD 256
#define DD 128
#define DFFV 256
#define CC 1000

#define NEGINF (-INFINITY)

// wt buffer float4 offsets (transposed-weight arena)
#define WT4_EW    0        // [64][128]  eW
#define WT4_QKV0  8192     // [32][128] x3 (q,k,v layer0)
#define WT4_QKV1  20480    // [32][128] x3 (layer1)
#define WT4_F1_0  32768    // [32][256]
#define WT4_F1_1  40960
#define WT4_F2_0  49152    // [64][128]
#define WT4_F2_1  57344
#define WT4_HW    65536    // [32][1000]
#define WT4_TOTAL 97536
#define WT_FLOATS (WT4_TOTAL * 4)

// monotonic float<->uint order-preserving encoding for atomicMax pooling
__device__ __forceinline__ unsigned keyenc(float f) {
  unsigned u = __float_as_uint(f);
  return (u & 0x80000000u) ? ~u : (u | 0x80000000u);
}
__device__ __forceinline__ float keydec(unsigned k) {
  unsigned u = (k & 0x80000000u) ? (k & 0x7fffffffu) : ~k;
  return __uint_as_float(u);
}

// NOTE: parameter names must not collide with .x/.y/.z/.w member accessors
#define FMAX4(ACC, XV, WV)                                              \
  ACC = fmaxf(ACC, (XV).x + (WV).x); ACC = fmaxf(ACC, (XV).y + (WV).y); \
  ACC = fmaxf(ACC, (XV).z + (WV).z); ACC = fmaxf(ACC, (XV).w + (WV).w);

// ===== K0: transpose all weights into [j4][out] float4 layout ============
__global__ __launch_bounds__(256) void transpose_weights_kernel(
    const float* __restrict__ eW, const float* __restrict__ qW0,
    const float* __restrict__ kW0, const float* __restrict__ vW0,
    const float* __restrict__ qW1, const float* __restrict__ kW1,
    const float* __restrict__ vW1, const float* __restrict__ f1W0,
    const float* __restrict__ f1W1, const float* __restrict__ f2W0,
    const float* __restrict__ f2W1, const float* __restrict__ hW,
    float* __restrict__ wt) {
  int idx = blockIdx.x * 256 + threadIdx.x;
  float4* wt4 = reinterpret_cast<float4*>(wt);
  const float* src;
  float4* dst;
  int local, OUT, J;
  if (idx < 8192) {
    src = eW; dst = wt4 + WT4_EW; local = idx; OUT = 128; J = 256;
  } else if (idx < 32768) {
    int s = (idx - 8192) >> 12; local = (idx - 8192) & 4095;
    src = (s == 0) ? qW0 : (s == 1) ? kW0 : (s == 2) ? vW0
        : (s == 3) ? qW1 : (s == 4) ? kW1 : vW1;
    dst = wt4 + WT4_QKV0 + s * 4096; OUT = 128; J = 128;
  } else if (idx < 49152) {
    int s = (idx - 32768) >> 13; local = (idx - 32768) & 8191;
    src = s ? f1W1 : f1W0; dst = wt4 + WT4_F1_0 + s * 8192; OUT = 256; J = 128;
  } else if (idx < 65536) {
    int s = (idx - 49152) >> 13; local = (idx - 49152) & 8191;
    src = s ? f2W1 : f2W0; dst = wt4 + WT4_F2_0 + s * 8192; OUT = 128; J = 256;
  } else if (idx < WT4_TOTAL) {
    src = hW; dst = wt4 + WT4_HW; local = idx - 65536; OUT = 1000; J = 128;
  } else {
    return;
  }
  int o, j4;
  if (OUT == 128) { o = local & 127; j4 = local >> 7; }
  else if (OUT == 256) { o = local & 255; j4 = local >> 8; }
  else { o = local % 1000; j4 = local / 1000; }
  dst[local] = *reinterpret_cast<const float4*>(src + (size_t)o * J + j4 * 4);
}

// ===== K1: embed + qkv(L0). grid (49,B), 384 threads, 4 rows/block =======
__global__ __launch_bounds__(384) void embed_qkv_kernel(
    const float* __restrict__ x, const float* __restrict__ wt,
    const float* __restrict__ pos, float* __restrict__ h,
    float* __restrict__ qg, float* __restrict__ KT, float* __restrict__ vg,
    unsigned* __restrict__ poolkey) {
  int nt = blockIdx.x, b = blockIdx.y, n0 = nt * 4;
  __shared__ float patch[4][PD];  // 4 KB
  __shared__ float hrow[4][DD];   // 2 KB
  __shared__ float mxs[4];
  int t = threadIdx.x;
  const float4* wt4 = reinterpret_cast<const float4*>(wt);
  if (nt == 0 && t < DD) poolkey[b * DD + t] = 0u;
  // stage 4 patches (one per row), 256 float4 loads
  if (t < 256) {
    int p = t >> 6, r = t & 63, pi = r >> 2, pj4 = r & 3;
    int n = n0 + p, gi = n / GG, gj = n % GG;
    float4 val = *reinterpret_cast<const float4*>(
        x + (size_t)(b * IMG + gi * PP + pi) * IMG + gj * PP + pj4 * 4);
    *reinterpret_cast<float4*>(&patch[p][pi * PP + pj4 * 4]) = val;
  }
  __syncthreads();
  // embed: threads 0..255, each handles 2 rows for its d; eWT coalesced
  if (t < 256) {
    int half = t >> 7, d = t & 127;
    int p0 = half * 2, p1 = p0 + 1;
    float a0 = NEGINF, a1 = NEGINF;
    const float4* W4 = wt4 + WT4_EW;  // [j4][d]
#pragma unroll 4
    for (int j4 = 0; j4 < PD / 4; j4++) {
      float4 wv = W4[j4 * DD + d];
      float4 x0 = *reinterpret_cast<const float4*>(&patch[p0][j4 * 4]);
      float4 x1 = *reinterpret_cast<const float4*>(&patch[p1][j4 * 4]);
      FMAX4(a0, x0, wv);
      FMAX4(a1, x1, wv);
    }
    float h0 = a0 + pos[(size_t)(n0 + p0) * DD + d];
    float h1v = a1 + pos[(size_t)(n0 + p1) * DD + d];
    hrow[p0][d] = h0; hrow[p1][d] = h1v;
    h[(size_t)(b * NN + n0 + p0) * DD + d] = h0;
    h[(size_t)(b * NN + n0 + p1) * DD + d] = h1v;
  }
  __syncthreads();
  // rowmax (pnorm constant) per row
  if (t < 128) {
    int r = t >> 5, l = t & 31;
    float m = fmaxf(fmaxf(hrow[r][l], hrow[r][l + 32]), fmaxf(hrow[r][l + 64], hrow[r][l + 96]));
#pragma unroll
    for (int mask = 16; mask >= 1; mask >>= 1) m = fmaxf(m, __shfl_xor(m, mask));
    if (l == 0) mxs[r] = m;
  }
  __syncthreads();
  // qkv: 192 threads, matrix m = t>>6, outputs i and i+64 (2 per x-read)
  if (t < 192) {
    int m = t >> 6, i = t & 63;
    const float4* W4 = wt4 + WT4_QKV0 + m * 4096;  // [j4][128]
    float a0[4], a1[4];
#pragma unroll
    for (int r = 0; r < 4; r++) { a0[r] = NEGINF; a1[r] = NEGINF; }
#pragma unroll 4
    for (int j4 = 0; j4 < DD / 4; j4++) {
      float4 wa = W4[j4 * DD + i];
      float4 wb = W4[j4 * DD + i + 64];
#pragma unroll
      for (int r = 0; r < 4; r++) {
        float4 xv = *reinterpret_cast<const float4*>(&hrow[r][j4 * 4]);
        FMAX4(a0[r], xv, wa);
        FMAX4(a1[r], xv, wb);
      }
    }
    if (m == 0) {
#pragma unroll
      for (int r = 0; r < 4; r++) {
        qg[(size_t)(b * NN + n0 + r) * DD + i] = a0[r] - mxs[r];
        qg[(size_t)(b * NN + n0 + r) * DD + i + 64] = a1[r] - mxs[r];
      }
    } else if (m == 1) {
#pragma unroll
      for (int r = 0; r < 4; r++) {
        KT[(((size_t)b * 32 + (i >> 2)) * NN + (n0 + r)) * 4 + (i & 3)] =
            a0[r] - mxs[r];
        KT[(((size_t)b * 32 + ((i + 64) >> 2)) * NN + (n0 + r)) * 4 + (i & 3)] =
            a1[r] - mxs[r];
      }
    } else {
#pragma unroll
      for (int r = 0; r < 4; r++) {
        vg[(size_t)(b * NN + n0 + r) * DD + i] = a0[r] - mxs[r];
        vg[(size_t)(b * NN + n0 + r) * DD + i + 64] = a1[r] - mxs[r];
      }
    }
  }
}

// ==== K2/K3: attn + ffn1 + ffn2 (+ next qkv | pool). grid (49,B), 384 ====
__global__ __launch_bounds__(384) void layer_kernel(
    const float* __restrict__ qg, const float* __restrict__ KTin,
    const float* __restrict__ vg, float* __restrict__ h,
    const float* __restrict__ wt, int f1off, int f2off,
    const float* __restrict__ tau, int qkvoff_next, float* __restrict__ qo,
    float* __restrict__ KTo, float* __restrict__ vo,
    unsigned* __restrict__ poolkey) {
  int nt = blockIdx.x, b = blockIdx.y, i0 = nt * 4;
  __shared__ float qs[4][DD];        // 2 KB
  __shared__ float hrow[4][DD];      // 2 KB (persistent x across the layer)
  __shared__ float4 sc4[NN];         // 3.1 KB  sc4[j] = scores rows 0..3
  __shared__ float h1s[4][DFFV];     // 4 KB
  __shared__ float scratch[12 * 4 * DD];  // 24 KB (ored / ffn2-part alias)
  __shared__ float red[2][4];
  __shared__ float mxs[4];
  int t = threadIdx.x;
  const float4* wt4 = reinterpret_cast<const float4*>(wt);
  // ---- stage qs (own q rows) and hrow (own h rows) ----
  if (t < 128) {
    float4 val = reinterpret_cast<const float4*>(qg + (size_t)(b * NN + i0) * DD)[t];
    *reinterpret_cast<float4*>(&qs[0][0] + t * 4) = val;
  } else if (t < 256) {
    int tt = t - 128;
    float4 val = reinterpret_cast<const float4*>(h + (size_t)(b * NN + i0) * DD)[tt];
    *reinterpret_cast<float4*>(&hrow[0][0] + tt * 4) = val;
  }
  __syncthreads();
  // ---- scores: 98 threads, keys t and t+98 (2 keys per qs-read) ----
  if (t < 98) {
    const float4* KT4 = reinterpret_cast<const float4*>(KTin);
    float sa[4], sb[4];
#pragma unroll
    for (int r = 0; r < 4; r++) { sa[r] = NEGINF; sb[r] = NEGINF; }
#pragma unroll 4
    for (int d4 = 0; d4 < DD / 4; d4++) {
      float4 ka = KT4[((size_t)b * 32 + d4) * NN + t];
      float4 kb = KT4[((size_t)b * 32 + d4) * NN + t + 98];
#pragma unroll
      for (int r = 0; r < 4; r++) {
        float4 qv = *reinterpret_cast<const float4*>(&qs[r][d4 * 4]);
        FMAX4(sa[r], qv, ka);
        FMAX4(sb[r], qv, kb);
      }
    }
    sc4[t] = make_float4(sa[0], sa[1], sa[2], sa[3]);
    sc4[t + 98] = make_float4(sb[0], sb[1], sb[2], sb[3]);
  }
  __syncthreads();
  // ---- PV: 12 j-groups x 32 d4-slots; sc4 read as one b128 ----
  {
    int d4 = t & 31, jg = t >> 5;
    float4 o0 = {NEGINF, NEGINF, NEGINF, NEGINF};
    float4 o1 = o0, o2 = o0, o3 = o0;
#pragma unroll 4
    for (int j = jg; j < NN; j += 12) {
      float4 vv = *reinterpret_cast<const float4*>(vg + (size_t)(b * NN + j) * DD + d4 * 4);
      float4 c = sc4[j];
      o0.x = fmaxf(o0.x, c.x + vv.x); o0.y = fmaxf(o0.y, c.x + vv.y);
      o0.z = fmaxf(o0.z, c.x + vv.z); o0.w = fmaxf(o0.w, c.x + vv.w);
      o1.x = fmaxf(o1.x, c.y + vv.x); o1.y = fmaxf(o1.y, c.y + vv.y);
      o1.z = fmaxf(o1.z, c.y + vv.z); o1.w = fmaxf(o1.w, c.y + vv.w);
      o2.x = fmaxf(o2.x, c.z + vv.x); o2.y = fmaxf(o2.y, c.z + vv.y);
      o2.z = fmaxf(o2.z, c.z + vv.z); o2.w = fmaxf(o2.w, c.z + vv.w);
      o3.x = fmaxf(o3.x, c.w + vv.x); o3.y = fmaxf(o3.y, c.w + vv.y);
      o3.z = fmaxf(o3.z, c.w + vv.z); o3.w = fmaxf(o3.w, c.w + vv.w);
    }
    *reinterpret_cast<float4*>(&scratch[((jg * 4 + 0) << 7) + d4 * 4]) = o0;
    *reinterpret_cast<float4*>(&scratch[((jg * 4 + 1) << 7) + d4 * 4]) = o1;
    *reinterpret_cast<float4*>(&scratch[((jg * 4 + 2) << 7) + d4 * 4]) = o2;
    *reinterpret_cast<float4*>(&scratch[((jg * 4 + 3) << 7) + d4 * 4]) = o3;
  }
  __syncthreads();
  // ---- combine 12 groups, pnorm over d, tropical residual into hrow ----
  float oacc[4];
  if (t < 128) {
    int lane = t & 63, wv = t >> 6;
#pragma unroll
    for (int r = 0; r < 4; r++) {
      float m = scratch[(r << 7) + t];
#pragma unroll
      for (int g = 1; g < 12; g++) m = fmaxf(m, scratch[((g * 4 + r) << 7) + t]);
      oacc[r] = m;
      float mv = m;
#pragma unroll
      for (int mask = 32; mask >= 1; mask >>= 1) mv = fmaxf(mv, __shfl_xor(mv, mask));
      if (lane == 0) red[wv][r] = mv;
    }
  }
  __syncthreads();
  if (t < 128) {
#pragma unroll
    for (int r = 0; r < 4; r++) {
      float omax = fmaxf(red[0][r], red[1][r]);
      hrow[r][t] = fmaxf(hrow[r][t], oacc[r] - omax);
    }
  }
  __syncthreads();
  // ---- ffn1 rowmax ----
  if (t < 128) {
    int r = t >> 5, l = t & 31;
    float m = fmaxf(fmaxf(hrow[r][l], hrow[r][l + 32]), fmaxf(hrow[r][l + 64], hrow[r][l + 96]));
#pragma unroll
    for (int mask = 16; mask >= 1; mask >>= 1) m = fmaxf(m, __shfl_xor(m, mask));
    if (l == 0) mxs[r] = m;
  }
  __syncthreads();
  // ---- ffn1: 128 threads, outputs t and t+128 (2 per x-read) ----
  if (t < 128) {
    float tv = tau[0];
    const float4* W4 = wt4 + f1off;  // [j4][256]
    float a0[4], a1[4];
#pragma unroll
    for (int r = 0; r < 4; r++) { a0[r] = NEGINF; a1[r] = NEGINF; }
#pragma unroll 4
    for (int j4 = 0; j4 < DD / 4; j4++) {
      float4 wa = W4[j4 * DFFV + t];
      float4 wb = W4[j4 * DFFV + t + 128];
#pragma unroll
      for (int r = 0; r < 4; r++) {
        float4 xv = *reinterpret_cast<const float4*>(&hrow[r][j4 * 4]);
        FMAX4(a0[r], xv, wa);
        FMAX4(a1[r], xv, wb);
      }
    }
#pragma unroll
    for (int r = 0; r < 4; r++) {
      h1s[r][t] = fmaxf(a0[r] - mxs[r], tv);
      h1s[r][t + 128] = fmaxf(a1[r] - mxs[r], tv);
    }
  }
  __syncthreads();
  // ---- ffn2: 128 threads, outputs i,i+64 x j-half jh (2 per x-read) ----
  if (t < 128) {
    int i = t & 63, jh = t >> 6;
    const float4* W4 = wt4 + f2off;  // [j4 0..63][128]
    float a0[4], a1[4];
#pragma unroll
    for (int r = 0; r < 4; r++) { a0[r] = NEGINF; a1[r] = NEGINF; }
#pragma unroll 4
    for (int j4 = 0; j4 < 32; j4++) {
      int jj = jh * 32 + j4;
      float4 wa = W4[jj * DD + i];
      float4 wb = W4[jj * DD + i + 64];
#pragma unroll
      for (int r = 0; r < 4; r++) {
        float4 yv = *reinterpret_cast<const float4*>(&h1s[r][jj * 4]);
        FMAX4(a0[r], yv, wa);
        FMAX4(a1[r], yv, wb);
      }
    }
#pragma unroll
    for (int r = 0; r < 4; r++) {
      scratch[((jh * 4 + r) << 7) + i] = a0[r];
      scratch[((jh * 4 + r) << 7) + i + 64] = a1[r];
    }
  }
  __syncthreads();
  float fm[4];
  if (t < 128) {
    int lane = t & 63, wv = t >> 6;
#pragma unroll
    for (int r = 0; r < 4; r++) {
      fm[r] = fmaxf(scratch[(r << 7) + t], scratch[((4 + r) << 7) + t]);
      float mv = fm[r];
#pragma unroll
      for (int mask = 32; mask >= 1; mask >>= 1) mv = fmaxf(mv, __shfl_xor(mv, mask));
      if (lane == 0) red[wv][r] = mv;
    }
  }
  __syncthreads();
  if (qkvoff_next < 0) {
    // final layer: fused global pooling over this block's 4 rows
    if (t < 128) {
      float pool = NEGINF;
#pragma unroll
      for (int r = 0; r < 4; r++) {
        float omax = fmaxf(red[0][r], red[1][r]);
        pool = fmaxf(pool, fmaxf(hrow[r][t], fm[r] - omax));
      }
      atomicMax(&poolkey[b * DD + t], keyenc(pool));
    }
    return;
  }
  // ---- ffn pnorm + residual; h hand-off; rowmax for next qkv ----
  if (t < 128) {
    int lane = t & 63, wv = t >> 6;
#pragma unroll
    for (int r = 0; r < 4; r++) {
      float omax = fmaxf(red[0][r], red[1][r]);
      float nh = fmaxf(hrow[r][t], fm[r] - omax);
      hrow[r][t] = nh;
      h[(size_t)(b * NN + i0 + r) * DD + t] = nh;
      float mv = nh;
#pragma unroll
      for (int mask = 32; mask >= 1; mask >>= 1) mv = fmaxf(mv, __shfl_xor(mv, mask));
      if (lane == 0) red[wv][r] = mv;
    }
  }
  __syncthreads();
  // ---- next-layer qkv: 192 threads, matrix m = t>>6, outputs i, i+64 ----
  if (t < 192) {
    int m = t >> 6, i = t & 63;
    const float4* W4 = wt4 + qkvoff_next + m * 4096;
    float a0[4], a1[4], mx[4];
#pragma unroll
    for (int r = 0; r < 4; r++) {
      a0[r] = NEGINF; a1[r] = NEGINF;
      mx[r] = fmaxf(red[0][r], red[1][r]);
    }
#pragma unroll 4
    for (int j4 = 0; j4 < DD / 4; j4++) {
      float4 wa = W4[j4 * DD + i];
      float4 wb = W4[j4 * DD + i + 64];
#pragma unroll
      for (int r = 0; r < 4; r++) {
        float4 xv = *reinterpret_cast<const float4*>(&hrow[r][j4 * 4]);
        FMAX4(a0[r], xv, wa);
        FMAX4(a1[r], xv, wb);
      }
    }
    if (m == 0) {
#pragma unroll
      for (int r = 0; r < 4; r++) {
        qo[(size_t)(b * NN + i0 + r) * DD + i] = a0[r] - mx[r];
        qo[(size_t)(b * NN + i0 + r) * DD + i + 64] = a1[r] - mx[r];
      }
    } else if (m == 1) {
#pragma unroll
      for (int r = 0; r < 4; r++) {
        KTo[(((size_t)b * 32 + (i >> 2)) * NN + (i0 + r)) * 4 + (i & 3)] =
            a0[r] - mx[r];
        KTo[(((size_t)b * 32 + ((i + 64) >> 2)) * NN + (i0 + r)) * 4 + (i & 3)] =
            a1[r] - mx[r];
      }
    } else {
#pragma unroll
      for (int r = 0; r < 4; r++) {
        vo[(size_t)(b * NN + i0 + r) * DD + i] = a0[r] - mx[r];
        vo[(size_t)(b * NN + i0 + r) * DD + i + 64] = a1[r] - mx[r];
      }
    }
  }
}

// ===== K4: head from pooled keys. grid (8, B), 128 threads; hWT coalesced =
__global__ __launch_bounds__(128) void head_kernel(
    const unsigned* __restrict__ poolkey, const float* __restrict__ wt,
    const float* __restrict__ lscale, float* __restrict__ out) {
  int cb = blockIdx.x, b = blockIdx.y;
  __shared__ float pooled[DD];
  int t = threadIdx.x;
  const float4* W4 = reinterpret_cast<const float4*>(wt) + WT4_HW;  // [k4][c]
  pooled[t] = keydec(poolkey[b * DD + t]);
  __syncthreads();
  if (t < 125) {
    int c = cb * 125 + t;
    float acc = NEGINF;
#pragma unroll 4
    for (int k4 = 0; k4 < DD / 4; k4++) {
      float4 wv = W4[k4 * CC + c];
      acc = fmaxf(acc, pooled[k4 * 4 + 0] + wv.x);
      acc = fmaxf(acc, pooled[k4 * 4 + 1] + wv.y);
      acc = fmaxf(acc, pooled[k4 * 4 + 2] + wv.z);
      acc = fmaxf(acc, pooled[k4 * 4 + 3] + wv.w);
    }
    out[(size_t)b * CC + c] = acc * lscale[0];
  }
}

extern "C" void kernel_launch(void* const* d_in, const int* in_sizes, int n_in,
                              void* d_out, int out_size, void* d_ws, size_t ws_size,
                              hipStream_t stream) {
  const float* x = (const float*)d_in[0];
  const float* embed_W = (const float*)d_in[1];
  const float* pos = (const float*)d_in[2];
  const float* qW0 = (const float*)d_in[3];
  const float* kW0 = (const float*)d_in[4];
  const float* vW0 = (const float*)d_in[5];
  const float* f1W0 = (const float*)d_in[6];
  const float* f2W0 = (const float*)d_in[7];
  const float* tau0 = (const float*)d_in[8];
  const float* qW1 = (const float*)d_in[9];
  const float* kW1 = (const float*)d_in[10];
  const float* vW1 = (const float*)d_in[11];
  const float* f1W1 = (const float*)d_in[12];
  const float* f2W1 = (const float*)d_in[13];
  const float* tau1 = (const float*)d_in[14];
  const float* headW = (const float*)d_in[15];
  const float* lscale = (const float*)d_in[16];
  float* out = (float*)d_out;

  float* ws = (float*)d_ws;
  size_t o = 0;
  float* h = ws + o; o += (size_t)BDIM * NN * DD;
  float* qb = ws + o; o += (size_t)BDIM * NN * DD;
  float* KT1 = ws + o; o += (size_t)BDIM * NN * DD;  // k transposed, layer0
  float* vb = ws + o; o += (size_t)BDIM * NN * DD;
  float* KT2 = ws + o; o += (size_t)BDIM * NN * DD;  // k transposed, layer1
  float* v2 = ws + o; o += (size_t)BDIM * NN * DD;
  unsigned* poolkey = (unsigned*)(ws + o); o += (size_t)BDIM * DD;
  float* wt = ws + o; o += (size_t)WT_FLOATS;

  // K0: transpose all weights into coalesced [j4][out] layout
  transpose_weights_kernel<<<dim3(WT4_TOTAL / 256 + 1), 256, 0, stream>>>(
      embed_W, qW0, kW0, vW0, qW1, kW1, vW1, f1W0, f1W1, f2W0, f2W1, headW, wt);
  // K1: embed + qkv(L0); also inits poolkey
  embed_qkv_kernel<<<dim3(49, BDIM), 384, 0, stream>>>(
      x, wt, pos, h, qb, KT1, vb, poolkey);
  // K2: attn(L0)+ffn(L0)+qkv(L1)
  layer_kernel<<<dim3(49, BDIM), 384, 0, stream>>>(
      qb, KT1, vb, h, wt, WT4_F1_0, WT4_F2_0, tau0, WT4_QKV1, qb, KT2, v2,
      poolkey);
  // K3: attn(L1)+ffn(L1) + fused global pooling
  layer_kernel<<<dim3(49, BDIM), 384, 0, stream>>>(
      qb, KT2, v2, h, wt, WT4_F1_1, WT4_F2_1, tau1, -1, nullptr, nullptr,
      nullptr, poolkey);
  // K4: head from pooled
  head_kernel<<<dim3(8, BDIM), 128, 0, stream>>>(poolkey, wt, lscale, out);
}

// Round 19
// 156.192 us; speedup vs baseline: 1.4422x; 1.4422x over previous
//
#include <hip/hip_runtime.h>
#include <math.h>

#define BDIM 8
#define IMG 224
#define PP 16
#define GG 14
#define NN 196
#define PD 256
#define DD 128
#define DFFV 256
#define CC 1000

#define NEGINF (-INFINITY)

// wt buffer float4 offsets (transposed-weight arena)
#define WT4_EW    0        // [64][128]  eW
#define WT4_QKV0  8192     // [32][128] x3 (q,k,v layer0)
#define WT4_QKV1  20480    // [32][128] x3 (layer1)
#define WT4_F1_0  32768    // [32][256]
#define WT4_F1_1  40960
#define WT4_F2_0  49152    // [64][128]
#define WT4_F2_1  57344
#define WT4_HW    65536    // [32][1000]
#define WT4_TOTAL 97536
#define WT_FLOATS (WT4_TOTAL * 4)

// monotonic float<->uint order-preserving encoding for atomicMax pooling
__device__ __forceinline__ unsigned keyenc(float f) {
  unsigned u = __float_as_uint(f);
  return (u & 0x80000000u) ? ~u : (u | 0x80000000u);
}
__device__ __forceinline__ float keydec(unsigned k) {
  unsigned u = (k & 0x80000000u) ? (k & 0x7fffffffu) : ~k;
  return __uint_as_float(u);
}

// ===== K0: transpose all weights into [j4][out] float4 layout ============
__global__ __launch_bounds__(256) void transpose_weights_kernel(
    const float* __restrict__ eW, const float* __restrict__ qW0,
    const float* __restrict__ kW0, const float* __restrict__ vW0,
    const float* __restrict__ qW1, const float* __restrict__ kW1,
    const float* __restrict__ vW1, const float* __restrict__ f1W0,
    const float* __restrict__ f1W1, const float* __restrict__ f2W0,
    const float* __restrict__ f2W1, const float* __restrict__ hW,
    float* __restrict__ wt) {
  int idx = blockIdx.x * 256 + threadIdx.x;
  float4* wt4 = reinterpret_cast<float4*>(wt);
  const float* src;
  float4* dst;
  int local, OUT, J;
  if (idx < 8192) {
    src = eW; dst = wt4 + WT4_EW; local = idx; OUT = 128; J = 256;
  } else if (idx < 32768) {
    int s = (idx - 8192) >> 12; local = (idx - 8192) & 4095;
    src = (s == 0) ? qW0 : (s == 1) ? kW0 : (s == 2) ? vW0
        : (s == 3) ? qW1 : (s == 4) ? kW1 : vW1;
    dst = wt4 + WT4_QKV0 + s * 4096; OUT = 128; J = 128;
  } else if (idx < 49152) {
    int s = (idx - 32768) >> 13; local = (idx - 32768) & 8191;
    src = s ? f1W1 : f1W0; dst = wt4 + WT4_F1_0 + s * 8192; OUT = 256; J = 128;
  } else if (idx < 65536) {
    int s = (idx - 49152) >> 13; local = (idx - 49152) & 8191;
    src = s ? f2W1 : f2W0; dst = wt4 + WT4_F2_0 + s * 8192; OUT = 128; J = 256;
  } else if (idx < WT4_TOTAL) {
    src = hW; dst = wt4 + WT4_HW; local = idx - 65536; OUT = 1000; J = 128;
  } else {
    return;
  }
  int o, j4;
  if (OUT == 128) { o = local & 127; j4 = local >> 7; }
  else if (OUT == 256) { o = local & 255; j4 = local >> 8; }
  else { o = local % 1000; j4 = local / 1000; }
  dst[local] = *reinterpret_cast<const float4*>(src + (size_t)o * J + j4 * 4);
}

// ===== K1: embed + qkv(L0). grid (49,B), 384 threads, 4 rows/block =======
__global__ __launch_bounds__(384) void embed_qkv_kernel(
    const float* __restrict__ x, const float* __restrict__ wt,
    const float* __restrict__ pos, float* __restrict__ h,
    float* __restrict__ qg, float* __restrict__ KT, float* __restrict__ vg,
    unsigned* __restrict__ poolkey) {
  int nt = blockIdx.x, b = blockIdx.y, n0 = nt * 4;
  __shared__ float patch[4][PD];  // 4 KB
  __shared__ float hrow[4][DD];   // 2 KB
  __shared__ float mxs[4];
  int t = threadIdx.x;
  const float4* wt4 = reinterpret_cast<const float4*>(wt);
  if (nt == 0 && t < DD) poolkey[b * DD + t] = 0u;
  // stage 4 patches (one per row), 256 float4 loads
  if (t < 256) {
    int p = t >> 6, r = t & 63, pi = r >> 2, pj4 = r & 3;
    int n = n0 + p, gi = n / GG, gj = n % GG;
    float4 val = *reinterpret_cast<const float4*>(
        x + (size_t)(b * IMG + gi * PP + pi) * IMG + gj * PP + pj4 * 4);
    *reinterpret_cast<float4*>(&patch[p][pi * PP + pj4 * 4]) = val;
  }
  __syncthreads();
  // embed: threads 0..255, each handles 2 rows for its d; eWT coalesced
  if (t < 256) {
    int half = t >> 7, d = t & 127;
    int p0 = half * 2, p1 = p0 + 1;
    float a0 = NEGINF, a1 = NEGINF;
    const float4* W4 = wt4 + WT4_EW;  // [j4][d]
#pragma unroll 4
    for (int j4 = 0; j4 < PD / 4; j4++) {
      float4 w = W4[j4 * DD + d];
      a0 = fmaxf(a0, patch[p0][j4 * 4 + 0] + w.x); a0 = fmaxf(a0, patch[p0][j4 * 4 + 1] + w.y);
      a0 = fmaxf(a0, patch[p0][j4 * 4 + 2] + w.z); a0 = fmaxf(a0, patch[p0][j4 * 4 + 3] + w.w);
      a1 = fmaxf(a1, patch[p1][j4 * 4 + 0] + w.x); a1 = fmaxf(a1, patch[p1][j4 * 4 + 1] + w.y);
      a1 = fmaxf(a1, patch[p1][j4 * 4 + 2] + w.z); a1 = fmaxf(a1, patch[p1][j4 * 4 + 3] + w.w);
    }
    float h0 = a0 + pos[(size_t)(n0 + p0) * DD + d];
    float h1v = a1 + pos[(size_t)(n0 + p1) * DD + d];
    hrow[p0][d] = h0; hrow[p1][d] = h1v;
    h[(size_t)(b * NN + n0 + p0) * DD + d] = h0;
    h[(size_t)(b * NN + n0 + p1) * DD + d] = h1v;
  }
  __syncthreads();
  // rowmax (pnorm constant) per row
  if (t < 128) {
    int r = t >> 5, l = t & 31;
    float m = fmaxf(fmaxf(hrow[r][l], hrow[r][l + 32]), fmaxf(hrow[r][l + 64], hrow[r][l + 96]));
#pragma unroll
    for (int mask = 16; mask >= 1; mask >>= 1) m = fmaxf(m, __shfl_xor(m, mask));
    if (l == 0) mxs[r] = m;
  }
  __syncthreads();
  // qkv: m in {0,1,2} -> q/k/v; coalesced WT reads; k written transposed
  {
    int m = t >> 7, i = t & 127;
    const float4* W4 = wt4 + WT4_QKV0 + m * 4096;  // [j4][i]
    float acc[4];
#pragma unroll
    for (int r = 0; r < 4; r++) acc[r] = NEGINF;
#pragma unroll 4
    for (int j4 = 0; j4 < DD / 4; j4++) {
      float4 w = W4[j4 * DD + i];
#pragma unroll
      for (int r = 0; r < 4; r++) {
        acc[r] = fmaxf(acc[r], hrow[r][j4 * 4 + 0] + w.x);
        acc[r] = fmaxf(acc[r], hrow[r][j4 * 4 + 1] + w.y);
        acc[r] = fmaxf(acc[r], hrow[r][j4 * 4 + 2] + w.z);
        acc[r] = fmaxf(acc[r], hrow[r][j4 * 4 + 3] + w.w);
      }
    }
    if (m == 0) {
#pragma unroll
      for (int r = 0; r < 4; r++)
        qg[(size_t)(b * NN + n0 + r) * DD + i] = acc[r] - mxs[r];
    } else if (m == 1) {
#pragma unroll
      for (int r = 0; r < 4; r++)
        KT[(((size_t)b * 32 + (i >> 2)) * NN + (n0 + r)) * 4 + (i & 3)] =
            acc[r] - mxs[r];
    } else {
#pragma unroll
      for (int r = 0; r < 4; r++)
        vg[(size_t)(b * NN + n0 + r) * DD + i] = acc[r] - mxs[r];
    }
  }
}

// ==== K2/K3: attn + ffn1 + ffn2 (+ next qkv | pool). grid (49,B), 384 ====
__global__ __launch_bounds__(384) void layer_kernel(
    const float* __restrict__ qg, const float* __restrict__ KTin,
    const float* __restrict__ vg, float* __restrict__ h,
    const float* __restrict__ wt, int f1off, int f2off,
    const float* __restrict__ tau, int qkvoff_next, float* __restrict__ qo,
    float* __restrict__ KTo, float* __restrict__ vo,
    unsigned* __restrict__ poolkey) {
  int nt = blockIdx.x, b = blockIdx.y, i0 = nt * 4;
  __shared__ float qs[4][DD];        // 2 KB
  __shared__ float hrow[4][DD];      // 2 KB (persistent x across the layer)
  __shared__ float4 sc4[NN];         // 3.1 KB  sc4[j] = scores rows 0..3
  __shared__ float h1s[4][DFFV];     // 4 KB
  __shared__ float scratch[12 * 4 * DD];  // 24 KB (ored / ffn2-part alias)
  __shared__ float red[2][4];
  __shared__ float mxs[4];
  int t = threadIdx.x;
  const float4* wt4 = reinterpret_cast<const float4*>(wt);
  // ---- stage qs (own q rows) and hrow (own h rows) ----
  if (t < 128) {
    float4 val = reinterpret_cast<const float4*>(qg + (size_t)(b * NN + i0) * DD)[t];
    *reinterpret_cast<float4*>(&qs[0][0] + t * 4) = val;
  } else if (t < 256) {
    int tt = t - 128;
    float4 val = reinterpret_cast<const float4*>(h + (size_t)(b * NN + i0) * DD)[tt];
    *reinterpret_cast<float4*>(&hrow[0][0] + tt * 4) = val;
  }
  __syncthreads();
  // ---- scores: thread t = key index j (full 196 width); sc4 packed write --
  if (t < NN) {
    const float4* KT4 = reinterpret_cast<const float4*>(KTin);
    float s0 = NEGINF, s1 = NEGINF, s2 = NEGINF, s3 = NEGINF;
#pragma unroll 4
    for (int d4 = 0; d4 < DD / 4; d4++) {
      float4 kv = KT4[((size_t)b * 32 + d4) * NN + t];
      s0 = fmaxf(s0, qs[0][d4 * 4 + 0] + kv.x); s0 = fmaxf(s0, qs[0][d4 * 4 + 1] + kv.y);
      s0 = fmaxf(s0, qs[0][d4 * 4 + 2] + kv.z); s0 = fmaxf(s0, qs[0][d4 * 4 + 3] + kv.w);
      s1 = fmaxf(s1, qs[1][d4 * 4 + 0] + kv.x); s1 = fmaxf(s1, qs[1][d4 * 4 + 1] + kv.y);
      s1 = fmaxf(s1, qs[1][d4 * 4 + 2] + kv.z); s1 = fmaxf(s1, qs[1][d4 * 4 + 3] + kv.w);
      s2 = fmaxf(s2, qs[2][d4 * 4 + 0] + kv.x); s2 = fmaxf(s2, qs[2][d4 * 4 + 1] + kv.y);
      s2 = fmaxf(s2, qs[2][d4 * 4 + 2] + kv.z); s2 = fmaxf(s2, qs[2][d4 * 4 + 3] + kv.w);
      s3 = fmaxf(s3, qs[3][d4 * 4 + 0] + kv.x); s3 = fmaxf(s3, qs[3][d4 * 4 + 1] + kv.y);
      s3 = fmaxf(s3, qs[3][d4 * 4 + 2] + kv.z); s3 = fmaxf(s3, qs[3][d4 * 4 + 3] + kv.w);
    }
    sc4[t] = make_float4(s0, s1, s2, s3);
  }
  __syncthreads();
  // ---- PV: 12 j-groups x 32 d4-slots; sc4 read as one broadcast b128 ----
  {
    int d4 = t & 31, jg = t >> 5;
    float4 o0 = {NEGINF, NEGINF, NEGINF, NEGINF};
    float4 o1 = o0, o2 = o0, o3 = o0;
#pragma unroll 4
    for (int j = jg; j < NN; j += 12) {
      float4 vv = *reinterpret_cast<const float4*>(vg + (size_t)(b * NN + j) * DD + d4 * 4);
      float4 c = sc4[j];
      o0.x = fmaxf(o0.x, c.x + vv.x); o0.y = fmaxf(o0.y, c.x + vv.y);
      o0.z = fmaxf(o0.z, c.x + vv.z); o0.w = fmaxf(o0.w, c.x + vv.w);
      o1.x = fmaxf(o1.x, c.y + vv.x); o1.y = fmaxf(o1.y, c.y + vv.y);
      o1.z = fmaxf(o1.z, c.y + vv.z); o1.w = fmaxf(o1.w, c.y + vv.w);
      o2.x = fmaxf(o2.x, c.z + vv.x); o2.y = fmaxf(o2.y, c.z + vv.y);
      o2.z = fmaxf(o2.z, c.z + vv.z); o2.w = fmaxf(o2.w, c.z + vv.w);
      o3.x = fmaxf(o3.x, c.w + vv.x); o3.y = fmaxf(o3.y, c.w + vv.y);
      o3.z = fmaxf(o3.z, c.w + vv.z); o3.w = fmaxf(o3.w, c.w + vv.w);
    }
    *reinterpret_cast<float4*>(&scratch[((jg * 4 + 0) << 7) + d4 * 4]) = o0;
    *reinterpret_cast<float4*>(&scratch[((jg * 4 + 1) << 7) + d4 * 4]) = o1;
    *reinterpret_cast<float4*>(&scratch[((jg * 4 + 2) << 7) + d4 * 4]) = o2;
    *reinterpret_cast<float4*>(&scratch[((jg * 4 + 3) << 7) + d4 * 4]) = o3;
  }
  __syncthreads();
  // ---- combine 12 groups, pnorm over d, tropical residual into hrow ----
  float oacc[4];
  if (t < 128) {
    int lane = t & 63, wv = t >> 6;
#pragma unroll
    for (int r = 0; r < 4; r++) {
      float m = scratch[(r << 7) + t];
#pragma unroll
      for (int g = 1; g < 12; g++) m = fmaxf(m, scratch[((g * 4 + r) << 7) + t]);
      oacc[r] = m;
      float mv = m;
#pragma unroll
      for (int mask = 32; mask >= 1; mask >>= 1) mv = fmaxf(mv, __shfl_xor(mv, mask));
      if (lane == 0) red[wv][r] = mv;
    }
  }
  __syncthreads();
  if (t < 128) {
#pragma unroll
    for (int r = 0; r < 4; r++) {
      float omax = fmaxf(red[0][r], red[1][r]);
      hrow[r][t] = fmaxf(hrow[r][t], oacc[r] - omax);
    }
  }
  __syncthreads();
  // ---- ffn1 rowmax ----
  if (t < 128) {
    int r = t >> 5, l = t & 31;
    float m = fmaxf(fmaxf(hrow[r][l], hrow[r][l + 32]), fmaxf(hrow[r][l + 64], hrow[r][l + 96]));
#pragma unroll
    for (int mask = 16; mask >= 1; mask >>= 1) m = fmaxf(m, __shfl_xor(m, mask));
    if (l == 0) mxs[r] = m;
  }
  __syncthreads();
  // ---- ffn1: 256 threads, coalesced f1WT reads ----
  if (t < DFFV) {
    float tv = tau[0];
    const float4* W4 = wt4 + f1off;  // [j4][o=256]
    float acc[4];
#pragma unroll
    for (int r = 0; r < 4; r++) acc[r] = NEGINF;
#pragma unroll 4
    for (int j4 = 0; j4 < DD / 4; j4++) {
      float4 w = W4[j4 * DFFV + t];
#pragma unroll
      for (int r = 0; r < 4; r++) {
        acc[r] = fmaxf(acc[r], hrow[r][j4 * 4 + 0] + w.x);
        acc[r] = fmaxf(acc[r], hrow[r][j4 * 4 + 1] + w.y);
        acc[r] = fmaxf(acc[r], hrow[r][j4 * 4 + 2] + w.z);
        acc[r] = fmaxf(acc[r], hrow[r][j4 * 4 + 3] + w.w);
      }
    }
#pragma unroll
    for (int r = 0; r < 4; r++) h1s[r][t] = fmaxf(acc[r] - mxs[r], tv);
  }
  __syncthreads();
  // ---- ffn2: 256 threads, coalesced f2WT reads; two DFF-halves ----
  if (t < DFFV) {
    int i = t & 127, jh = t >> 7;
    const float4* W4 = wt4 + f2off;  // [jg 0..63][i=128]
    float acc[4];
#pragma unroll
    for (int r = 0; r < 4; r++) acc[r] = NEGINF;
#pragma unroll 4
    for (int j4 = 0; j4 < 32; j4++) {
      float4 w = W4[(jh * 32 + j4) * DD + i];
      int jb = jh * 128 + j4 * 4;
#pragma unroll
      for (int r = 0; r < 4; r++) {
        acc[r] = fmaxf(acc[r], h1s[r][jb + 0] + w.x);
        acc[r] = fmaxf(acc[r], h1s[r][jb + 1] + w.y);
        acc[r] = fmaxf(acc[r], h1s[r][jb + 2] + w.z);
        acc[r] = fmaxf(acc[r], h1s[r][jb + 3] + w.w);
      }
    }
#pragma unroll
    for (int r = 0; r < 4; r++) scratch[((jh * 4 + r) << 7) + i] = acc[r];
  }
  __syncthreads();
  float fm[4];
  if (t < 128) {
    int lane = t & 63, wv = t >> 6;
#pragma unroll
    for (int r = 0; r < 4; r++) {
      fm[r] = fmaxf(scratch[(r << 7) + t], scratch[((4 + r) << 7) + t]);
      float mv = fm[r];
#pragma unroll
      for (int mask = 32; mask >= 1; mask >>= 1) mv = fmaxf(mv, __shfl_xor(mv, mask));
      if (lane == 0) red[wv][r] = mv;
    }
  }
  __syncthreads();
  if (qkvoff_next < 0) {
    // final layer: fused global pooling over this block's 4 rows
    if (t < 128) {
      float pool = NEGINF;
#pragma unroll
      for (int r = 0; r < 4; r++) {
        float omax = fmaxf(red[0][r], red[1][r]);
        pool = fmaxf(pool, fmaxf(hrow[r][t], fm[r] - omax));
      }
      atomicMax(&poolkey[b * DD + t], keyenc(pool));
    }
    return;
  }
  // ---- ffn pnorm + residual; h hand-off; rowmax for next qkv ----
  if (t < 128) {
    int lane = t & 63, wv = t >> 6;
#pragma unroll
    for (int r = 0; r < 4; r++) {
      float omax = fmaxf(red[0][r], red[1][r]);
      float nh = fmaxf(hrow[r][t], fm[r] - omax);
      hrow[r][t] = nh;
      h[(size_t)(b * NN + i0 + r) * DD + t] = nh;
      float mv = nh;
#pragma unroll
      for (int mask = 32; mask >= 1; mask >>= 1) mv = fmaxf(mv, __shfl_xor(mv, mask));
      if (lane == 0) red[wv][r] = mv;
    }
  }
  __syncthreads();
  // ---- next-layer qkv: 384 threads, coalesced WT reads; k transposed ----
  {
    int m = t >> 7, i = t & 127;
    const float4* W4 = wt4 + qkvoff_next + m * 4096;
    float acc[4], mx[4];
#pragma unroll
    for (int r = 0; r < 4; r++) {
      acc[r] = NEGINF;
      mx[r] = fmaxf(red[0][r], red[1][r]);
    }
#pragma unroll 4
    for (int j4 = 0; j4 < DD / 4; j4++) {
      float4 w = W4[j4 * DD + i];
#pragma unroll
      for (int r = 0; r < 4; r++) {
        acc[r] = fmaxf(acc[r], hrow[r][j4 * 4 + 0] + w.x);
        acc[r] = fmaxf(acc[r], hrow[r][j4 * 4 + 1] + w.y);
        acc[r] = fmaxf(acc[r], hrow[r][j4 * 4 + 2] + w.z);
        acc[r] = fmaxf(acc[r], hrow[r][j4 * 4 + 3] + w.w);
      }
    }
    if (m == 0) {
#pragma unroll
      for (int r = 0; r < 4; r++)
        qo[(size_t)(b * NN + i0 + r) * DD + i] = acc[r] - mx[r];
    } else if (m == 1) {
#pragma unroll
      for (int r = 0; r < 4; r++)
        KTo[(((size_t)b * 32 + (i >> 2)) * NN + (i0 + r)) * 4 + (i & 3)] =
            acc[r] - mx[r];
    } else {
#pragma unroll
      for (int r = 0; r < 4; r++)
        vo[(size_t)(b * NN + i0 + r) * DD + i] = acc[r] - mx[r];
    }
  }
}

// ===== K4: head from pooled keys. grid (8, B), 128 threads; hWT coalesced =
__global__ __launch_bounds__(128) void head_kernel(
    const unsigned* __restrict__ poolkey, const float* __restrict__ wt,
    const float* __restrict__ lscale, float* __restrict__ out) {
  int cb = blockIdx.x, b = blockIdx.y;
  __shared__ float pooled[DD];
  int t = threadIdx.x;
  const float4* W4 = reinterpret_cast<const float4*>(wt) + WT4_HW;  // [k4][c]
  pooled[t] = keydec(poolkey[b * DD + t]);
  __syncthreads();
  if (t < 125) {
    int c = cb * 125 + t;
    float acc = NEGINF;
#pragma unroll 4
    for (int k4 = 0; k4 < DD / 4; k4++) {
      float4 w = W4[k4 * CC + c];
      acc = fmaxf(acc, pooled[k4 * 4 + 0] + w.x);
      acc = fmaxf(acc, pooled[k4 * 4 + 1] + w.y);
      acc = fmaxf(acc, pooled[k4 * 4 + 2] + w.z);
      acc = fmaxf(acc, pooled[k4 * 4 + 3] + w.w);
    }
    out[(size_t)b * CC + c] = acc * lscale[0];
  }
}

extern "C" void kernel_launch(void* const* d_in, const int* in_sizes, int n_in,
                              void* d_out, int out_size, void* d_ws, size_t ws_size,
                              hipStream_t stream) {
  const float* x = (const float*)d_in[0];
  const float* embed_W = (const float*)d_in[1];
  const float* pos = (const float*)d_in[2];
  const float* qW0 = (const float*)d_in[3];
  const float* kW0 = (const float*)d_in[4];
  const float* vW0 = (const float*)d_in[5];
  const float* f1W0 = (const float*)d_in[6];
  const float* f2W0 = (const float*)d_in[7];
  const float* tau0 = (const float*)d_in[8];
  const float* qW1 = (const float*)d_in[9];
  const float* kW1 = (const float*)d_in[10];
  const float* vW1 = (const float*)d_in[11];
  const float* f1W1 = (const float*)d_in[12];
  const float* f2W1 = (const float*)d_in[13];
  const float* tau1 = (const float*)d_in[14];
  const float* headW = (const float*)d_in[15];
  const float* lscale = (const float*)d_in[16];
  float* out = (float*)d_out;

  float* ws = (float*)d_ws;
  size_t o = 0;
  float* h = ws + o; o += (size_t)BDIM * NN * DD;
  float* qb = ws + o; o += (size_t)BDIM * NN * DD;
  float* KT1 = ws + o; o += (size_t)BDIM * NN * DD;  // k transposed, layer0
  float* vb = ws + o; o += (size_t)BDIM * NN * DD;
  float* KT2 = ws + o; o += (size_t)BDIM * NN * DD;  // k transposed, layer1
  float* v2 = ws + o; o += (size_t)BDIM * NN * DD;
  unsigned* poolkey = (unsigned*)(ws + o); o += (size_t)BDIM * DD;
  float* wt = ws + o; o += (size_t)WT_FLOATS;

  // K0: transpose all weights into coalesced [j4][out] layout
  transpose_weights_kernel<<<dim3(WT4_TOTAL / 256 + 1), 256, 0, stream>>>(
      embed_W, qW0, kW0, vW0, qW1, kW1, vW1, f1W0, f1W1, f2W0, f2W1, headW, wt);
  // K1: embed + qkv(L0); also inits poolkey
  embed_qkv_kernel<<<dim3(49, BDIM), 384, 0, stream>>>(
      x, wt, pos, h, qb, KT1, vb, poolkey);
  // K2: attn(L0)+ffn(L0)+qkv(L1)
  layer_kernel<<<dim3(49, BDIM), 384, 0, stream>>>(
      qb, KT1, vb, h, wt, WT4_F1_0, WT4_F2_0, tau0, WT4_QKV1, qb, KT2, v2,
      poolkey);
  // K3: attn(L1)+ffn(L1) + fused global pooling
  layer_kernel<<<dim3(49, BDIM), 384, 0, stream>>>(
      qb, KT2, v2, h, wt, WT4_F1_1, WT4_F2_1, tau1, -1, nullptr, nullptr,
      nullptr, poolkey);
  // K4: head from pooled
  head_kernel<<<dim3(8, BDIM), 128, 0, stream>>>(poolkey, wt, lscale, out);
}

// Round 20
// 155.319 us; speedup vs baseline: 1.4503x; 1.0056x over previous
//
#include <hip/hip_runtime.h>
#include <math.h>

#define BDIM 8
#define IMG 224
#define PP 16
#define GG 14
#define NN 196
#define PD 256
#define DD 128
#define DFFV 256
#define CC 1000

#define NEGINF (-INFINITY)

// wt buffer float4 offsets (transposed-weight arena)
#define WT4_EW    0        // [64][128]  eW
#define WT4_QKV0  8192     // [32][128] x3 (q,k,v layer0)
#define WT4_QKV1  20480    // [32][128] x3 (layer1)
#define WT4_F1_0  32768    // [32][256]
#define WT4_F1_1  40960
#define WT4_F2_0  49152    // [64][128]
#define WT4_F2_1  57344
#define WT4_HW    65536    // [32][1000]
#define WT4_TOTAL 97536
#define WT_FLOATS (WT4_TOTAL * 4)

// monotonic float<->uint order-preserving encoding for atomicMax pooling
__device__ __forceinline__ unsigned keyenc(float f) {
  unsigned u = __float_as_uint(f);
  return (u & 0x80000000u) ? ~u : (u | 0x80000000u);
}
__device__ __forceinline__ float keydec(unsigned k) {
  unsigned u = (k & 0x80000000u) ? (k & 0x7fffffffu) : ~k;
  return __uint_as_float(u);
}

// ===== K0: transpose all weights into [j4][out] float4 layout ============
__global__ __launch_bounds__(256) void transpose_weights_kernel(
    const float* __restrict__ eW, const float* __restrict__ qW0,
    const float* __restrict__ kW0, const float* __restrict__ vW0,
    const float* __restrict__ qW1, const float* __restrict__ kW1,
    const float* __restrict__ vW1, const float* __restrict__ f1W0,
    const float* __restrict__ f1W1, const float* __restrict__ f2W0,
    const float* __restrict__ f2W1, const float* __restrict__ hW,
    float* __restrict__ wt) {
  int idx = blockIdx.x * 256 + threadIdx.x;
  float4* wt4 = reinterpret_cast<float4*>(wt);
  const float* src;
  float4* dst;
  int local, OUT, J;
  if (idx < 8192) {
    src = eW; dst = wt4 + WT4_EW; local = idx; OUT = 128; J = 256;
  } else if (idx < 32768) {
    int s = (idx - 8192) >> 12; local = (idx - 8192) & 4095;
    src = (s == 0) ? qW0 : (s == 1) ? kW0 : (s == 2) ? vW0
        : (s == 3) ? qW1 : (s == 4) ? kW1 : vW1;
    dst = wt4 + WT4_QKV0 + s * 4096; OUT = 128; J = 128;
  } else if (idx < 49152) {
    int s = (idx - 32768) >> 13; local = (idx - 32768) & 8191;
    src = s ? f1W1 : f1W0; dst = wt4 + WT4_F1_0 + s * 8192; OUT = 256; J = 128;
  } else if (idx < 65536) {
    int s = (idx - 49152) >> 13; local = (idx - 49152) & 8191;
    src = s ? f2W1 : f2W0; dst = wt4 + WT4_F2_0 + s * 8192; OUT = 128; J = 256;
  } else if (idx < WT4_TOTAL) {
    src = hW; dst = wt4 + WT4_HW; local = idx - 65536; OUT = 1000; J = 128;
  } else {
    return;
  }
  int o, j4;
  if (OUT == 128) { o = local & 127; j4 = local >> 7; }
  else if (OUT == 256) { o = local & 255; j4 = local >> 8; }
  else { o = local % 1000; j4 = local / 1000; }
  dst[local] = *reinterpret_cast<const float4*>(src + (size_t)o * J + j4 * 4);
}

// ===== K1: embed + qkv(L0). grid (49,B), 384 threads, 4 rows/block =======
// Embed PD-reduce split 3 ways across full 384-thread width (chain 64->22).
__global__ __launch_bounds__(384) void embed_qkv_kernel(
    const float* __restrict__ x, const float* __restrict__ wt,
    const float* __restrict__ pos, float* __restrict__ h,
    float* __restrict__ qg, float* __restrict__ KT, float* __restrict__ vg,
    unsigned* __restrict__ poolkey) {
  int nt = blockIdx.x, b = blockIdx.y, n0 = nt * 4;
  __shared__ float patch[4][PD];        // 4 KB
  __shared__ float hrow[4][DD];         // 2 KB
  __shared__ float empart[3][4][DD];    // 6 KB (3-way embed partials)
  __shared__ float mxs[4];
  int t = threadIdx.x;
  const float4* wt4 = reinterpret_cast<const float4*>(wt);
  if (nt == 0 && t < DD) poolkey[b * DD + t] = 0u;
  // stage 4 patches (one per row), 256 float4 loads
  if (t < 256) {
    int p = t >> 6, r = t & 63, pi = r >> 2, pj4 = r & 3;
    int n = n0 + p, gi = n / GG, gj = n % GG;
    float4 val = *reinterpret_cast<const float4*>(
        x + (size_t)(b * IMG + gi * PP + pi) * IMG + gj * PP + pj4 * 4);
    *reinterpret_cast<float4*>(&patch[p][pi * PP + pj4 * 4]) = val;
  }
  __syncthreads();
  // embed: 384 threads, (g = t>>7 in {0,1,2}, d = t&127); each g covers a
  // j4-range (22/22/20 iters) for ALL 4 rows; partials in empart.
  {
    int g = t >> 7, d = t & 127;
    int j0 = g * 22, j1 = (g == 2) ? 64 : (j0 + 22);
    const float4* W4 = wt4 + WT4_EW;  // [j4][d]
    float a0 = NEGINF, a1 = NEGINF, a2 = NEGINF, a3 = NEGINF;
    for (int j4 = j0; j4 < j1; j4++) {
      float4 w = W4[j4 * DD + d];
      float4 p0 = *reinterpret_cast<const float4*>(&patch[0][j4 * 4]);
      float4 p1 = *reinterpret_cast<const float4*>(&patch[1][j4 * 4]);
      float4 p2 = *reinterpret_cast<const float4*>(&patch[2][j4 * 4]);
      float4 p3 = *reinterpret_cast<const float4*>(&patch[3][j4 * 4]);
      a0 = fmaxf(a0, p0.x + w.x); a0 = fmaxf(a0, p0.y + w.y);
      a0 = fmaxf(a0, p0.z + w.z); a0 = fmaxf(a0, p0.w + w.w);
      a1 = fmaxf(a1, p1.x + w.x); a1 = fmaxf(a1, p1.y + w.y);
      a1 = fmaxf(a1, p1.z + w.z); a1 = fmaxf(a1, p1.w + w.w);
      a2 = fmaxf(a2, p2.x + w.x); a2 = fmaxf(a2, p2.y + w.y);
      a2 = fmaxf(a2, p2.z + w.z); a2 = fmaxf(a2, p2.w + w.w);
      a3 = fmaxf(a3, p3.x + w.x); a3 = fmaxf(a3, p3.y + w.y);
      a3 = fmaxf(a3, p3.z + w.z); a3 = fmaxf(a3, p3.w + w.w);
    }
    empart[g][0][d] = a0; empart[g][1][d] = a1;
    empart[g][2][d] = a2; empart[g][3][d] = a3;
  }
  __syncthreads();
  // combine 3 partials + pos; write h; hrow
  if (t < 128) {
#pragma unroll
    for (int r = 0; r < 4; r++) {
      float hv = fmaxf(fmaxf(empart[0][r][t], empart[1][r][t]), empart[2][r][t])
                 + pos[(size_t)(n0 + r) * DD + t];
      hrow[r][t] = hv;
      h[(size_t)(b * NN + n0 + r) * DD + t] = hv;
    }
  }
  __syncthreads();
  // rowmax (pnorm constant) per row
  if (t < 128) {
    int r = t >> 5, l = t & 31;
    float m = fmaxf(fmaxf(hrow[r][l], hrow[r][l + 32]), fmaxf(hrow[r][l + 64], hrow[r][l + 96]));
#pragma unroll
    for (int mask = 16; mask >= 1; mask >>= 1) m = fmaxf(m, __shfl_xor(m, mask));
    if (l == 0) mxs[r] = m;
  }
  __syncthreads();
  // qkv: m in {0,1,2} -> q/k/v; coalesced WT reads; k written transposed
  {
    int m = t >> 7, i = t & 127;
    const float4* W4 = wt4 + WT4_QKV0 + m * 4096;  // [j4][i]
    float acc[4];
#pragma unroll
    for (int r = 0; r < 4; r++) acc[r] = NEGINF;
#pragma unroll 4
    for (int j4 = 0; j4 < DD / 4; j4++) {
      float4 w = W4[j4 * DD + i];
#pragma unroll
      for (int r = 0; r < 4; r++) {
        acc[r] = fmaxf(acc[r], hrow[r][j4 * 4 + 0] + w.x);
        acc[r] = fmaxf(acc[r], hrow[r][j4 * 4 + 1] + w.y);
        acc[r] = fmaxf(acc[r], hrow[r][j4 * 4 + 2] + w.z);
        acc[r] = fmaxf(acc[r], hrow[r][j4 * 4 + 3] + w.w);
      }
    }
    if (m == 0) {
#pragma unroll
      for (int r = 0; r < 4; r++)
        qg[(size_t)(b * NN + n0 + r) * DD + i] = acc[r] - mxs[r];
    } else if (m == 1) {
#pragma unroll
      for (int r = 0; r < 4; r++)
        KT[(((size_t)b * 32 + (i >> 2)) * NN + (n0 + r)) * 4 + (i & 3)] =
            acc[r] - mxs[r];
    } else {
#pragma unroll
      for (int r = 0; r < 4; r++)
        vg[(size_t)(b * NN + n0 + r) * DD + i] = acc[r] - mxs[r];
    }
  }
}

// ==== K2/K3: attn + ffn1 + ffn2 (+ next qkv | pool). grid (49,B), 384 ====
__global__ __launch_bounds__(384) void layer_kernel(
    const float* __restrict__ qg, const float* __restrict__ KTin,
    const float* __restrict__ vg, float* __restrict__ h,
    const float* __restrict__ wt, int f1off, int f2off,
    const float* __restrict__ tau, int qkvoff_next, float* __restrict__ qo,
    float* __restrict__ KTo, float* __restrict__ vo,
    unsigned* __restrict__ poolkey) {
  int nt = blockIdx.x, b = blockIdx.y, i0 = nt * 4;
  __shared__ float qs[4][DD];        // 2 KB
  __shared__ float hrow[4][DD];      // 2 KB (persistent x across the layer)
  __shared__ float sc[4][NN];        // 3.1 KB
  __shared__ float h1s[4][DFFV];     // 4 KB
  __shared__ float scratch[12 * 4 * DD];  // 24 KB (ored / ffn2-part alias)
  __shared__ float red[2][4];
  __shared__ float mxs[4];
  int t = threadIdx.x;
  const float4* wt4 = reinterpret_cast<const float4*>(wt);
  // ---- stage qs (own q rows) and hrow (own h rows) ----
  if (t < 128) {
    float4 val = reinterpret_cast<const float4*>(qg + (size_t)(b * NN + i0) * DD)[t];
    *reinterpret_cast<float4*>(&qs[0][0] + t * 4) = val;
  } else if (t < 256) {
    int tt = t - 128;
    float4 val = reinterpret_cast<const float4*>(h + (size_t)(b * NN + i0) * DD)[tt];
    *reinterpret_cast<float4*>(&hrow[0][0] + tt * 4) = val;
  }
  __syncthreads();
  // ---- scores: thread t = key index j; KT coalesced reads ----
  if (t < NN) {
    const float4* KT4 = reinterpret_cast<const float4*>(KTin);
    float s0 = NEGINF, s1 = NEGINF, s2 = NEGINF, s3 = NEGINF;
#pragma unroll 4
    for (int d4 = 0; d4 < DD / 4; d4++) {
      float4 kv = KT4[((size_t)b * 32 + d4) * NN + t];
      s0 = fmaxf(s0, qs[0][d4 * 4 + 0] + kv.x); s0 = fmaxf(s0, qs[0][d4 * 4 + 1] + kv.y);
      s0 = fmaxf(s0, qs[0][d4 * 4 + 2] + kv.z); s0 = fmaxf(s0, qs[0][d4 * 4 + 3] + kv.w);
      s1 = fmaxf(s1, qs[1][d4 * 4 + 0] + kv.x); s1 = fmaxf(s1, qs[1][d4 * 4 + 1] + kv.y);
      s1 = fmaxf(s1, qs[1][d4 * 4 + 2] + kv.z); s1 = fmaxf(s1, qs[1][d4 * 4 + 3] + kv.w);
      s2 = fmaxf(s2, qs[2][d4 * 4 + 0] + kv.x); s2 = fmaxf(s2, qs[2][d4 * 4 + 1] + kv.y);
      s2 = fmaxf(s2, qs[2][d4 * 4 + 2] + kv.z); s2 = fmaxf(s2, qs[2][d4 * 4 + 3] + kv.w);
      s3 = fmaxf(s3, qs[3][d4 * 4 + 0] + kv.x); s3 = fmaxf(s3, qs[3][d4 * 4 + 1] + kv.y);
      s3 = fmaxf(s3, qs[3][d4 * 4 + 2] + kv.z); s3 = fmaxf(s3, qs[3][d4 * 4 + 3] + kv.w);
    }
    sc[0][t] = s0; sc[1][t] = s1; sc[2][t] = s2; sc[3][t] = s3;
  }
  __syncthreads();
  // ---- PV: 12 j-groups x 32 d4-slots ----
  {
    int d4 = t & 31, jg = t >> 5;
    float4 o0 = {NEGINF, NEGINF, NEGINF, NEGINF};
    float4 o1 = o0, o2 = o0, o3 = o0;
#pragma unroll 4
    for (int j = jg; j < NN; j += 12) {
      float4 vv = *reinterpret_cast<const float4*>(vg + (size_t)(b * NN + j) * DD + d4 * 4);
      float c0 = sc[0][j], c1 = sc[1][j], c2 = sc[2][j], c3 = sc[3][j];
      o0.x = fmaxf(o0.x, c0 + vv.x); o0.y = fmaxf(o0.y, c0 + vv.y);
      o0.z = fmaxf(o0.z, c0 + vv.z); o0.w = fmaxf(o0.w, c0 + vv.w);
      o1.x = fmaxf(o1.x, c1 + vv.x); o1.y = fmaxf(o1.y, c1 + vv.y);
      o1.z = fmaxf(o1.z, c1 + vv.z); o1.w = fmaxf(o1.w, c1 + vv.w);
      o2.x = fmaxf(o2.x, c2 + vv.x); o2.y = fmaxf(o2.y, c2 + vv.y);
      o2.z = fmaxf(o2.z, c2 + vv.z); o2.w = fmaxf(o2.w, c2 + vv.w);
      o3.x = fmaxf(o3.x, c3 + vv.x); o3.y = fmaxf(o3.y, c3 + vv.y);
      o3.z = fmaxf(o3.z, c3 + vv.z); o3.w = fmaxf(o3.w, c3 + vv.w);
    }
    *reinterpret_cast<float4*>(&scratch[((jg * 4 + 0) << 7) + d4 * 4]) = o0;
    *reinterpret_cast<float4*>(&scratch[((jg * 4 + 1) << 7) + d4 * 4]) = o1;
    *reinterpret_cast<float4*>(&scratch[((jg * 4 + 2) << 7) + d4 * 4]) = o2;
    *reinterpret_cast<float4*>(&scratch[((jg * 4 + 3) << 7) + d4 * 4]) = o3;
  }
  __syncthreads();
  // ---- combine 12 groups, pnorm over d, tropical residual into hrow ----
  float oacc[4];
  if (t < 128) {
    int lane = t & 63, wv = t >> 6;
#pragma unroll
    for (int r = 0; r < 4; r++) {
      float m = scratch[(r << 7) + t];
#pragma unroll
      for (int g = 1; g < 12; g++) m = fmaxf(m, scratch[((g * 4 + r) << 7) + t]);
      oacc[r] = m;
      float mv = m;
#pragma unroll
      for (int mask = 32; mask >= 1; mask >>= 1) mv = fmaxf(mv, __shfl_xor(mv, mask));
      if (lane == 0) red[wv][r] = mv;
    }
  }
  __syncthreads();
  if (t < 128) {
#pragma unroll
    for (int r = 0; r < 4; r++) {
      float omax = fmaxf(red[0][r], red[1][r]);
      hrow[r][t] = fmaxf(hrow[r][t], oacc[r] - omax);
    }
  }
  __syncthreads();
  // ---- ffn1 rowmax ----
  if (t < 128) {
    int r = t >> 5, l = t & 31;
    float m = fmaxf(fmaxf(hrow[r][l], hrow[r][l + 32]), fmaxf(hrow[r][l + 64], hrow[r][l + 96]));
#pragma unroll
    for (int mask = 16; mask >= 1; mask >>= 1) m = fmaxf(m, __shfl_xor(m, mask));
    if (l == 0) mxs[r] = m;
  }
  __syncthreads();
  // ---- ffn1: coalesced f1WT reads ----
  if (t < DFFV) {
    float tv = tau[0];
    const float4* W4 = wt4 + f1off;  // [j4][o=256]
    float acc[4];
#pragma unroll
    for (int r = 0; r < 4; r++) acc[r] = NEGINF;
#pragma unroll 4
    for (int j4 = 0; j4 < DD / 4; j4++) {
      float4 w = W4[j4 * DFFV + t];
#pragma unroll
      for (int r = 0; r < 4; r++) {
        acc[r] = fmaxf(acc[r], hrow[r][j4 * 4 + 0] + w.x);
        acc[r] = fmaxf(acc[r], hrow[r][j4 * 4 + 1] + w.y);
        acc[r] = fmaxf(acc[r], hrow[r][j4 * 4 + 2] + w.z);
        acc[r] = fmaxf(acc[r], hrow[r][j4 * 4 + 3] + w.w);
      }
    }
#pragma unroll
    for (int r = 0; r < 4; r++) h1s[r][t] = fmaxf(acc[r] - mxs[r], tv);
  }
  __syncthreads();
  // ---- ffn2: coalesced f2WT reads; two DFF-halves ----
  if (t < DFFV) {
    int i = t & 127, jh = t >> 7;
    const float4* W4 = wt4 + f2off;  // [jg 0..63][i=128]
    float acc[4];
#pragma unroll
    for (int r = 0; r < 4; r++) acc[r] = NEGINF;
#pragma unroll 4
    for (int j4 = 0; j4 < 32; j4++) {
      float4 w = W4[(jh * 32 + j4) * DD + i];
      int jb = jh * 128 + j4 * 4;
#pragma unroll
      for (int r = 0; r < 4; r++) {
        acc[r] = fmaxf(acc[r], h1s[r][jb + 0] + w.x);
        acc[r] = fmaxf(acc[r], h1s[r][jb + 1] + w.y);
        acc[r] = fmaxf(acc[r], h1s[r][jb + 2] + w.z);
        acc[r] = fmaxf(acc[r], h1s[r][jb + 3] + w.w);
      }
    }
#pragma unroll
    for (int r = 0; r < 4; r++) scratch[((jh * 4 + r) << 7) + i] = acc[r];
  }
  __syncthreads();
  float fm[4];
  if (t < 128) {
    int lane = t & 63, wv = t >> 6;
#pragma unroll
    for (int r = 0; r < 4; r++) {
      fm[r] = fmaxf(scratch[(r << 7) + t], scratch[((4 + r) << 7) + t]);
      float mv = fm[r];
#pragma unroll
      for (int mask = 32; mask >= 1; mask >>= 1) mv = fmaxf(mv, __shfl_xor(mv, mask));
      if (lane == 0) red[wv][r] = mv;
    }
  }
  __syncthreads();
  if (qkvoff_next < 0) {
    // final layer: fused global pooling over this block's 4 rows
    if (t < 128) {
      float pool = NEGINF;
#pragma unroll
      for (int r = 0; r < 4; r++) {
        float omax = fmaxf(red[0][r], red[1][r]);
        pool = fmaxf(pool, fmaxf(hrow[r][t], fm[r] - omax));
      }
      atomicMax(&poolkey[b * DD + t], keyenc(pool));
    }
    return;
  }
  // ---- ffn pnorm + residual; h hand-off; rowmax for next qkv ----
  if (t < 128) {
    int lane = t & 63, wv = t >> 6;
#pragma unroll
    for (int r = 0; r < 4; r++) {
      float omax = fmaxf(red[0][r], red[1][r]);
      float nh = fmaxf(hrow[r][t], fm[r] - omax);
      hrow[r][t] = nh;
      h[(size_t)(b * NN + i0 + r) * DD + t] = nh;
      float mv = nh;
#pragma unroll
      for (int mask = 32; mask >= 1; mask >>= 1) mv = fmaxf(mv, __shfl_xor(mv, mask));
      if (lane == 0) red[wv][r] = mv;
    }
  }
  __syncthreads();
  // ---- next-layer qkv: coalesced WT reads; k written transposed ----
  {
    int m = t >> 7, i = t & 127;
    const float4* W4 = wt4 + qkvoff_next + m * 4096;
    float acc[4], mx[4];
#pragma unroll
    for (int r = 0; r < 4; r++) {
      acc[r] = NEGINF;
      mx[r] = fmaxf(red[0][r], red[1][r]);
    }
#pragma unroll 4
    for (int j4 = 0; j4 < DD / 4; j4++) {
      float4 w = W4[j4 * DD + i];
#pragma unroll
      for (int r = 0; r < 4; r++) {
        acc[r] = fmaxf(acc[r], hrow[r][j4 * 4 + 0] + w.x);
        acc[r] = fmaxf(acc[r], hrow[r][j4 * 4 + 1] + w.y);
        acc[r] = fmaxf(acc[r], hrow[r][j4 * 4 + 2] + w.z);
        acc[r] = fmaxf(acc[r], hrow[r][j4 * 4 + 3] + w.w);
      }
    }
    if (m == 0) {
#pragma unroll
      for (int r = 0; r < 4; r++)
        qo[(size_t)(b * NN + i0 + r) * DD + i] = acc[r] - mx[r];
    } else if (m == 1) {
#pragma unroll
      for (int r = 0; r < 4; r++)
        KTo[(((size_t)b * 32 + (i >> 2)) * NN + (i0 + r)) * 4 + (i & 3)] =
            acc[r] - mx[r];
    } else {
#pragma unroll
      for (int r = 0; r < 4; r++)
        vo[(size_t)(b * NN + i0 + r) * DD + i] = acc[r] - mx[r];
    }
  }
}

// ===== K4: head from pooled keys. grid (8, B), 128 threads; hWT coalesced =
__global__ __launch_bounds__(128) void head_kernel(
    const unsigned* __restrict__ poolkey, const float* __restrict__ wt,
    const float* __restrict__ lscale, float* __restrict__ out) {
  int cb = blockIdx.x, b = blockIdx.y;
  __shared__ float pooled[DD];
  int t = threadIdx.x;
  const float4* W4 = reinterpret_cast<const float4*>(wt) + WT4_HW;  // [k4][c]
  pooled[t] = keydec(poolkey[b * DD + t]);
  __syncthreads();
  if (t < 125) {
    int c = cb * 125 + t;
    float acc = NEGINF;
#pragma unroll 4
    for (int k4 = 0; k4 < DD / 4; k4++) {
      float4 w = W4[k4 * CC + c];
      acc = fmaxf(acc, pooled[k4 * 4 + 0] + w.x);
      acc = fmaxf(acc, pooled[k4 * 4 + 1] + w.y);
      acc = fmaxf(acc, pooled[k4 * 4 + 2] + w.z);
      acc = fmaxf(acc, pooled[k4 * 4 + 3] + w.w);
    }
    out[(size_t)b * CC + c] = acc * lscale[0];
  }
}

extern "C" void kernel_launch(void* const* d_in, const int* in_sizes, int n_in,
                              void* d_out, int out_size, void* d_ws, size_t ws_size,
                              hipStream_t stream) {
  const float* x = (const float*)d_in[0];
  const float* embed_W = (const float*)d_in[1];
  const float* pos = (const float*)d_in[2];
  const float* qW0 = (const float*)d_in[3];
  const float* kW0 = (const float*)d_in[4];
  const float* vW0 = (const float*)d_in[5];
  const float* f1W0 = (const float*)d_in[6];
  const float* f2W0 = (const float*)d_in[7];
  const float* tau0 = (const float*)d_in[8];
  const float* qW1 = (const float*)d_in[9];
  const float* kW1 = (const float*)d_in[10];
  const float* vW1 = (const float*)d_in[11];
  const float* f1W1 = (const float*)d_in[12];
  const float* f2W1 = (const float*)d_in[13];
  const float* tau1 = (const float*)d_in[14];
  const float* headW = (const float*)d_in[15];
  const float* lscale = (const float*)d_in[16];
  float* out = (float*)d_out;

  float* ws = (float*)d_ws;
  size_t o = 0;
  float* h = ws + o; o += (size_t)BDIM * NN * DD;
  float* qb = ws + o; o += (size_t)BDIM * NN * DD;
  float* KT1 = ws + o; o += (size_t)BDIM * NN * DD;  // k transposed, layer0
  float* vb = ws + o; o += (size_t)BDIM * NN * DD;
  float* KT2 = ws + o; o += (size_t)BDIM * NN * DD;  // k transposed, layer1
  float* v2 = ws + o; o += (size_t)BDIM * NN * DD;
  unsigned* poolkey = (unsigned*)(ws + o); o += (size_t)BDIM * DD;
  float* wt = ws + o; o += (size_t)WT_FLOATS;

  // K0: transpose all weights into coalesced [j4][out] layout
  transpose_weights_kernel<<<dim3(WT4_TOTAL / 256 + 1), 256, 0, stream>>>(
      embed_W, qW0, kW0, vW0, qW1, kW1, vW1, f1W0, f1W1, f2W0, f2W1, headW, wt);
  // K1: embed + qkv(L0); also inits poolkey
  embed_qkv_kernel<<<dim3(49, BDIM), 384, 0, stream>>>(
      x, wt, pos, h, qb, KT1, vb, poolkey);
  // K2: attn(L0)+ffn(L0)+qkv(L1)
  layer_kernel<<<dim3(49, BDIM), 384, 0, stream>>>(
      qb, KT1, vb, h, wt, WT4_F1_0, WT4_F2_0, tau0, WT4_QKV1, qb, KT2, v2,
      poolkey);
  // K3: attn(L1)+ffn(L1) + fused global pooling
  layer_kernel<<<dim3(49, BDIM), 384, 0, stream>>>(
      qb, KT2, v2, h, wt, WT4_F1_1, WT4_F2_1, tau1, -1, nullptr, nullptr,
      nullptr, poolkey);
  // K4: head from pooled
  head_kernel<<<dim3(8, BDIM), 128, 0, stream>>>(poolkey, wt, lscale, out);
}